// Round 1
// 218.348 us; speedup vs baseline: 1.0602x; 1.0602x over previous
//
#include <hip/hip_runtime.h>

// Path signature depth 5, d=10, L=128, B=256 — fully thread-private scan+GEMM.
//
// Restructure vs previous version: each thread owns one (g, m3) pair and ALL
// 10 c4 columns. Scan state (s1,s2,s3) and the derived W1/W0 are computed and
// consumed in-thread, so the W1/W0 LDS panels and every main-loop barrier are
// gone. Per thread: S4[10] level-4 prefix + acc[10][10] level-5 accumulator in
// registers (100 useful FMAs per segment out of ~140 VALU ops). LDS holds only
// the 127x10 delta table (6 KB); per segment a thread issues 3 uniform vector
// loads (de) + 3 per-lane b32 (dg,dc2,dc3), software-pipelined 1 segment ahead
// (ping-pong deA/deB), so LDS latency hides under the 10x12-FMA c4 loop.
//
// Block = 512 threads = 5 g's (500 active, 97.7% lane util), grid = 2*B = 512
// blocks (2 exact rounds over 256 CUs). VGPR ~150 -> 2 waves/SIMD; ILP-10 in
// the acc FMAs keeps the VALU issue-bound anyway.

#define D10    10
#define LPATH  128
#define NSEG   127
#define RS     12          // dT row stride (floats, 48B -> float4-aligned)
#define BLOCK  512
#define OUT_PER_B 111110

__global__ __launch_bounds__(BLOCK, 2) void sig_kernel(
        const float* __restrict__ path,   // [B][D10][LPATH]
        float* __restrict__ out)          // [B][OUT_PER_B]
{
    __shared__ __align__(16) float dT[(NSEG + 1) * RS];   // +1 guard row

    const int tid = threadIdx.x;
    const int bb  = blockIdx.x;
    const int b   = bb >> 1;              // batch
    const int gh  = (bb & 1) * 5;         // g half: 0..4 or 5..9
    const float* pb = path + (size_t)b * (D10 * LPATH);

    // ---- delta table (127 segments x 10 channels) ----
    for (int idx = tid; idx < NSEG * D10; idx += BLOCK) {
        int t = idx / D10, c = idx - t * D10;
        dT[t * RS + c] = pb[c * LPATH + t + 1] - pb[c * LPATH + t];
    }
    if (tid < RS) dT[NSEG * RS + tid] = 0.f;   // guard row (prefetch overrun)

    const int gg = tid / 100;             // 0..4 (g within half)
    const int m3 = tid - gg * 100;        // 0..99
    const int g  = gh + gg;
    const int c2 = m3 / 10;
    const int c3 = m3 - c2 * 10;

    float s1 = 0.f, s2 = 0.f, s3 = 0.f;   // levels 1-3 scan state
    float S4[D10];                         // level-4 prefix row (all c4)
    float acc[D10][D10];                   // level-5 accumulator [c4][e]
#pragma unroll
    for (int i = 0; i < D10; ++i) {
        S4[i] = 0.f;
#pragma unroll
        for (int e = 0; e < D10; ++e) acc[i][e] = 0.f;
    }

    __syncthreads();   // dT ready; no further barriers needed

    if (tid < 500) {
        auto load = [&](float (&de)[D10], float &dg, float &d2, float &d3, int t) {
            const float* dr = &dT[t * RS];
            float4 A  = *(const float4*)dr;          // uniform-address broadcast
            float4 Bv = *(const float4*)(dr + 4);
            float2 Cv = *(const float2*)(dr + 8);
            de[0] = A.x;  de[1] = A.y;  de[2] = A.z;  de[3] = A.w;
            de[4] = Bv.x; de[5] = Bv.y; de[6] = Bv.z; de[7] = Bv.w;
            de[8] = Cv.x; de[9] = Cv.y;
            dg = dr[g]; d2 = dr[c2]; d3 = dr[c3];    // per-lane b32, conflict-free
        };
        auto step = [&](const float (&de)[D10], float dg, float d2, float d3) {
            // levels 1-3 scan + Abel weights (verified recurrences, unchanged)
            float u24 = s2 + (s1 + dg * 0.25f)       * d2 * (1.f / 3.f);
            float u25 = s2 + (s1 + dg * 0.2f)        * d2 * 0.25f;
            float u23 = s2 + (s1 + dg * (1.f / 3.f)) * d2 * 0.5f;
            float w1  = s3 + u24 * d3 * 0.5f;
            float w0  = s3 + u25 * d3 * (1.f / 3.f);
            s3 += u23 * d3;
            s2 += (s1 + dg * 0.5f) * d2;
            s1 += dg;
            float w0h = 0.5f * w0;
#pragma unroll
            for (int c4 = 0; c4 < D10; ++c4) {
                float dcv = de[c4];
                float c4v = fmaf(w0h, dcv, S4[c4]);   // C4(u) = S4 + 0.5*W0*d[c4]
                S4[c4] = fmaf(w1, dcv, S4[c4]);       // S4(u+1) = S4 + W1*d[c4]
#pragma unroll
                for (int e = 0; e < D10; ++e)
                    acc[c4][e] = fmaf(c4v, de[e], acc[c4][e]);
            }
        };

        // ping-pong software pipeline: prefetch segment t+1 while computing t
        float deA[D10], deB[D10];
        float dgA, d2A, d3A, dgB, d2B, d3B;
        load(deA, dgA, d2A, d3A, 0);
#pragma unroll 1
        for (int t = 0; t + 2 <= NSEG; t += 2) {
            load(deB, dgB, d2B, d3B, t + 1);
            step(deA, dgA, d2A, d3A);                 // segment t
            load(deA, dgA, d2A, d3A, t + 2);          // t+2 <= 127 (guard row)
            step(deB, dgB, d2B, d3B);                 // segment t+1
        }
        step(deA, dgA, d2A, d3A);                     // segment 126 (tail)

        // ---- epilogue: all state in registers, no barrier ----
        float* ob = out + (size_t)b * OUT_PER_B;
        if (m3 == 0) ob[g] = s1;                      // level 1
        if (c3 == 0) ob[10 + g * 10 + c2] = s2;       // level 2
        ob[110 + g * 100 + m3] = s3;                  // level 3
        float* o4 = ob + 1110 + g * 1000 + m3 * 10;   // level 4 (8B aligned)
#pragma unroll
        for (int e = 0; e < D10; e += 2)
            *(float2*)&o4[e] = make_float2(S4[e], S4[e + 1]);
        float* o5 = ob + 11110 + (size_t)g * 10000 + (size_t)m3 * 100; // level 5
#pragma unroll
        for (int c4 = 0; c4 < D10; ++c4)
#pragma unroll
            for (int e = 0; e < D10; e += 2)
                *(float2*)&o5[c4 * 10 + e] =
                    make_float2(acc[c4][e], acc[c4][e + 1]);
    }
}

extern "C" void kernel_launch(void* const* d_in, const int* in_sizes, int n_in,
                              void* d_out, int out_size, void* d_ws, size_t ws_size,
                              hipStream_t stream) {
    const float* path = (const float*)d_in[0];
    float* out = (float*)d_out;
    int B = in_sizes[0] / (D10 * LPATH);   // 256
    sig_kernel<<<B * 2, BLOCK, 0, stream>>>(path, out);
}

// Round 2
// 204.202 us; speedup vs baseline: 1.1336x; 1.0693x over previous
//
#include <hip/hip_runtime.h>

// Path signature depth 5, d=10, L=128, B=256 — MFMA reformulation.
//
// Exact algebra on the verified recurrence: with R_u[e] = p_e[127]-p_e[u+1],
//   level5[row,c4,e] = sum_u W1_u[row]*(d_u[c4]*R_u[e]) + W0h_u[row]*(d_u[c4]*d_u[e])
//   level4[row,c4]   = sum_u W1_u[row]*d_u[c4]   (aug columns 100..109, B0=0, R'=1)
// => per batch a [1000 x 254] x [254 x 110] GEMM; A = scan output (W1,W0h
// interleaved along K: k=2u+term), B shared by all rows. fp32 accuracy via
// 2-way bf16 split (truncation hi + residual lo), all 4 cross-product MFMAs.
//
// 4 blocks/batch (q = 250-row slice), 512 threads, KC=16 segments/chunk
// (K=32 bf16 = exactly the 4 k-groups of mfma_f32_16x16x32_bf16). Panels are
// k-group-major [kg][row][8] so both fragment reads and packed uint4 writes
// are optimal b128 patterns. Scan (levels 1-3, threads<250) is the verified
// fp32 recurrence, unchanged. LDS ~56 KB -> 2 blocks/CU.

#define D10    10
#define LPATH  128
#define NSEG   127
#define BLOCK  512
#define NROW   256     // panel rows per block (250 active)
#define NROWA  250
#define NCOL   112     // 100 level5 cols + 10 level4-aug + 2 pad
#define NCOLA  110
#define KC     16      // segments per chunk -> K = 32 bf16
#define NCH    8       // 8*16 = 128 >= 127 (u=127 is a zero pad column)
#define SD     132     // dTT/RT row stride (floats)
#define OUT_PER_B 111110

typedef __attribute__((ext_vector_type(8))) short bf16x8;
typedef __attribute__((ext_vector_type(4))) float f32x4;

// pack bf16(x),bf16(y) (truncation) into hi word; packed residuals into lo.
__device__ __forceinline__ unsigned pack_split(float x, float y, unsigned &lo)
{
    unsigned xb = __float_as_uint(x), yb = __float_as_uint(y);
    float xr = x - __uint_as_float(xb & 0xffff0000u);
    float yr = y - __uint_as_float(yb & 0xffff0000u);
    lo = (__float_as_uint(xr) >> 16) | (__float_as_uint(yr) & 0xffff0000u);
    return (xb >> 16) | (yb & 0xffff0000u);
}

__global__ __launch_bounds__(BLOCK, 2) void sig_kernel(
        const float* __restrict__ path,   // [B][D10][LPATH]
        float* __restrict__ out)          // [B][OUT_PER_B]
{
    __shared__ __align__(16) float dTT[D10 * SD];   // d_u[c], t-contiguous
    __shared__ __align__(16) float RT [D10 * SD];   // suffix sums R_u[c]
    __shared__ __align__(16) short Ahi[4 * NROW * 8];  // [kg][row][8] bf16
    __shared__ __align__(16) short Alo[4 * NROW * 8];
    __shared__ __align__(16) short Bhi[4 * NCOL * 8];  // [kg][col][8] bf16
    __shared__ __align__(16) short Blo[4 * NCOL * 8];

    const int tid = threadIdx.x;
    const int bb  = blockIdx.x;
    const int b   = bb >> 2;
    const int q   = bb & 3;                 // 250-row slice of the 1000 rows
    const float* pb = path + (size_t)b * (D10 * LPATH);

    // ---- delta + suffix tables (R telescopes: no serial scan needed) ----
    for (int idx = tid; idx < D10 * SD; idx += BLOCK) {
        int c = idx / SD, t = idx - c * SD;
        float d = 0.f, r = 0.f;
        if (t < NSEG) {
            float p1 = pb[c * LPATH + t + 1];
            d = p1 - pb[c * LPATH + t];
            r = pb[c * LPATH + NSEG] - p1;
        }
        dTT[idx] = d;
        RT [idx] = r;
    }
    // zero pad A rows (250..255) and B cols (110..111) once
    for (int idx = tid; idx < 4 * (NROW - NROWA) * 8; idx += BLOCK) {
        int kg = idx / ((NROW - NROWA) * 8);
        int rem = idx - kg * ((NROW - NROWA) * 8);
        int o = (kg * NROW + NROWA) * 8 + rem;
        Ahi[o] = 0; Alo[o] = 0;
    }
    if (tid < 4 * 2 * 8) {
        int kg = tid >> 4, rem = tid & 15;
        int o = (kg * NCOL + NCOLA) * 8 + rem;
        Bhi[o] = 0; Blo[o] = 0;
    }

    // ---- scan identity (threads < 250): row = q*250 + tid -> (g,c2,c3) ----
    const int grow = q * NROWA + tid;
    const int g   = grow / 100;
    const int m3  = grow - g * 100;
    const int c2  = m3 / 10;
    const int c3  = m3 - c2 * 10;
    const int goff = g * SD, c2off = c2 * SD, c3off = c3 * SD;

    // ---- B-build identity (threads < 440): col = tid>>2, kgroup = tid&3 ----
    const int cb  = tid >> 2;
    const int kgB = tid & 3;
    int c4o = 0, ebo = 0;
    if (cb < 100) { int c4 = cb / 10; ebo = (cb - c4 * 10) * SD; c4o = c4 * SD; }
    else          { c4o = (cb - 100) * SD; }

    const int lane = tid & 63;
    const int wv   = tid >> 6;      // 8 waves x 32 rows each
    const int rl   = lane & 15;
    const int kgl  = lane >> 4;

    float s1 = 0.f, s2 = 0.f, s3 = 0.f;
    f32x4 acc[2][7];
#pragma unroll
    for (int i = 0; i < 2; ++i)
#pragma unroll
        for (int nt = 0; nt < 7; ++nt) acc[i][nt] = f32x4{0.f, 0.f, 0.f, 0.f};

    __syncthreads();

    for (int ch = 0; ch < NCH; ++ch) {
        const int kc0 = ch * KC;
        // ---- produce: scan -> A panels (verified recurrence, fp32) ----
        if (tid < NROWA) {
#pragma unroll
            for (int w0 = 0; w0 < KC; w0 += 4) {
                float4 g4 = *(const float4*)&dTT[goff  + kc0 + w0];
                float4 a4 = *(const float4*)&dTT[c2off + kc0 + w0];
                float4 b4 = *(const float4*)&dTT[c3off + kc0 + w0];
                float ga[4] = {g4.x, g4.y, g4.z, g4.w};
                float aa[4] = {a4.x, a4.y, a4.z, a4.w};
                float ba[4] = {b4.x, b4.y, b4.z, b4.w};
                unsigned hw[4], lw[4];
#pragma unroll
                for (int j = 0; j < 4; ++j) {
                    float dg = ga[j], d2 = aa[j], d3 = ba[j];
                    float u24 = s2 + (s1 + dg * 0.25f)     * d2 * (1.f / 3.f);
                    float u25 = s2 + (s1 + dg * 0.2f)      * d2 * 0.25f;
                    float u23 = s2 + (s1 + dg * (1.f/3.f)) * d2 * 0.5f;
                    float w1v = s3 + u24 * d3 * 0.5f;
                    float w0h = 0.5f * (s3 + u25 * d3 * (1.f / 3.f));
                    s3 += u23 * d3;
                    s2 += (s1 + dg * 0.5f) * d2;
                    s1 += dg;                       // d=0 pads leave state unchanged
                    hw[j] = pack_split(w1v, w0h, lw[j]);   // k=2u: W1, k=2u+1: W0h
                }
                const int ai = ((w0 >> 2) * NROW + tid) * 8;
                *(uint4*)&Ahi[ai] = make_uint4(hw[0], hw[1], hw[2], hw[3]);
                *(uint4*)&Alo[ai] = make_uint4(lw[0], lw[1], lw[2], lw[3]);
            }
        }
        // ---- produce: B panels (shared across all rows) ----
        if (tid < 440) {
            const int u0 = kc0 + kgB * 4;
            float4 d4 = *(const float4*)&dTT[c4o + u0];
            float da[4] = {d4.x, d4.y, d4.z, d4.w};
            unsigned hw[4], lw[4];
            if (cb < 100) {
                float4 e4 = *(const float4*)&dTT[ebo + u0];
                float4 r4 = *(const float4*)&RT [ebo + u0];
                float ea[4] = {e4.x, e4.y, e4.z, e4.w};
                float ra[4] = {r4.x, r4.y, r4.z, r4.w};
#pragma unroll
                for (int j = 0; j < 4; ++j)
                    hw[j] = pack_split(da[j] * ra[j], da[j] * ea[j], lw[j]);
            } else {   // level-4 aug cols: B1 = d, B0 = 0
#pragma unroll
                for (int j = 0; j < 4; ++j)
                    hw[j] = pack_split(da[j], 0.f, lw[j]);
            }
            const int bi = (kgB * NCOL + cb) * 8;
            *(uint4*)&Bhi[bi] = make_uint4(hw[0], hw[1], hw[2], hw[3]);
            *(uint4*)&Blo[bi] = make_uint4(lw[0], lw[1], lw[2], lw[3]);
        }
        __syncthreads();
        // ---- consume: 2 M-tiles x 7 N-tiles x 4 split-term MFMAs ----
        {
            bf16x8 bh[7], bl[7];
#pragma unroll
            for (int nt = 0; nt < 7; ++nt) {
                const int bi = (kgl * NCOL + nt * 16 + rl) * 8;
                bh[nt] = *(const bf16x8*)&Bhi[bi];
                bl[nt] = *(const bf16x8*)&Blo[bi];
            }
#pragma unroll
            for (int i = 0; i < 2; ++i) {
                const int ai = (kgl * NROW + wv * 32 + i * 16 + rl) * 8;
                bf16x8 ah = *(const bf16x8*)&Ahi[ai];
                bf16x8 al = *(const bf16x8*)&Alo[ai];
#pragma unroll
                for (int nt = 0; nt < 7; ++nt) {
                    acc[i][nt] = __builtin_amdgcn_mfma_f32_16x16x32_bf16(ah, bh[nt], acc[i][nt], 0, 0, 0);
                    acc[i][nt] = __builtin_amdgcn_mfma_f32_16x16x32_bf16(ah, bl[nt], acc[i][nt], 0, 0, 0);
                    acc[i][nt] = __builtin_amdgcn_mfma_f32_16x16x32_bf16(al, bh[nt], acc[i][nt], 0, 0, 0);
                    acc[i][nt] = __builtin_amdgcn_mfma_f32_16x16x32_bf16(al, bl[nt], acc[i][nt], 0, 0, 0);
                }
            }
        }
        __syncthreads();
    }

    // ---- epilogue ----
    float* ob = out + (size_t)b * OUT_PER_B;
    if (tid < NROWA) {
        ob[110 + grow] = s3;                       // level 3
        if (c3 == 0) ob[10 + g * 10 + c2] = s2;    // level 2
        if (m3 == 0) ob[g] = s1;                   // level 1
    }
    // D layout (m89-verified): col = lane&15, row = (lane>>4)*4 + reg
#pragma unroll
    for (int i = 0; i < 2; ++i) {
#pragma unroll
        for (int r = 0; r < 4; ++r) {
            const int prow = wv * 32 + i * 16 + kgl * 4 + r;
            if (prow < NROWA) {
                const int gr = q * NROWA + prow;
#pragma unroll
                for (int nt = 0; nt < 7; ++nt) {
                    const int col = nt * 16 + rl;
                    const float v = acc[i][nt][r];
                    if (col < 100)
                        ob[11110 + (size_t)gr * 100 + col] = v;   // level 5
                    else if (col < NCOLA)
                        ob[1110 + gr * 10 + (col - 100)] = v;     // level 4
                }
            }
        }
    }
}

extern "C" void kernel_launch(void* const* d_in, const int* in_sizes, int n_in,
                              void* d_out, int out_size, void* d_ws, size_t ws_size,
                              hipStream_t stream) {
    const float* path = (const float*)d_in[0];
    float* out = (float*)d_out;
    int B = in_sizes[0] / (D10 * LPATH);   // 256
    sig_kernel<<<B * 4, BLOCK, 0, stream>>>(path, out);
}

// Round 3
// 192.993 us; speedup vs baseline: 1.1995x; 1.0581x over previous
//
#include <hip/hip_runtime.h>

// Path signature depth 5, d=10, L=128, B=256 — MFMA, fused produce/consume.
//
// Same verified algebra as round 2: per batch a [1000 x 254] x [254 x 110]
// GEMM (K = 2 terms/segment: W1*d[c4]*R[e] + W0h*d[c4]*d[e]; level-4 rides as
// aug cols 100..109), fp32 accuracy via 2-way bf16 split, 4 cross MFMAs.
// Numerics byte-identical to the passing round-2 kernel.
//
// Scheduling change: A/B panels are double-buffered (+46KB -> 102KB LDS,
// 1 block/CU) and each chunk iteration is ONE barrier phase containing
// {fragment loads of chunk ch} + {produce of chunk ch+1} + {56 MFMAs}.
// Scan VALU (waves 0-3), B-build (moved to waves 4-7), LDS reads and MFMA
// co-schedule across the SIMD's 2 resident waves instead of being serialized
// into produce|consume phases. launch_bounds(512,1) -> 256-VGPR budget.

#define D10    10
#define LPATH  128
#define NSEG   127
#define BLOCK  512
#define NROW   256     // panel rows per block (250 active)
#define NROWA  250
#define NCOL   112     // 100 level5 cols + 10 level4-aug + 2 pad
#define NCOLA  110
#define KC     16      // segments per chunk -> K = 32 bf16
#define NCH    8       // 8*16 = 128 >= 127 (u=127 zero pad)
#define SD     132     // dTT/RT row stride (floats)
#define OUT_PER_B 111110

typedef __attribute__((ext_vector_type(8))) short bf16x8;
typedef __attribute__((ext_vector_type(4))) float f32x4;

// pack bf16(x),bf16(y) (truncation) into hi word; packed residuals into lo.
__device__ __forceinline__ unsigned pack_split(float x, float y, unsigned &lo)
{
    unsigned xb = __float_as_uint(x), yb = __float_as_uint(y);
    float xr = x - __uint_as_float(xb & 0xffff0000u);
    float yr = y - __uint_as_float(yb & 0xffff0000u);
    lo = (__float_as_uint(xr) >> 16) | (__float_as_uint(yr) & 0xffff0000u);
    return (xb >> 16) | (yb & 0xffff0000u);
}

__global__ __launch_bounds__(BLOCK, 1) void sig_kernel(
        const float* __restrict__ path,   // [B][D10][LPATH]
        float* __restrict__ out)          // [B][OUT_PER_B]
{
    __shared__ __align__(16) float dTT[D10 * SD];          // d_u[c]
    __shared__ __align__(16) float RT [D10 * SD];          // R_u[c] suffix
    __shared__ __align__(16) short AhiS[2][4 * NROW * 8];  // [buf][kg][row][8]
    __shared__ __align__(16) short AloS[2][4 * NROW * 8];
    __shared__ __align__(16) short BhiS[2][4 * NCOL * 8];  // [buf][kg][col][8]
    __shared__ __align__(16) short BloS[2][4 * NCOL * 8];

    const int tid = threadIdx.x;
    const int bb  = blockIdx.x;
    const int b   = bb >> 2;
    const int q   = bb & 3;                 // 250-row slice of the 1000 rows
    const float* pb = path + (size_t)b * (D10 * LPATH);

    // ---- delta + suffix tables (R telescopes; t>=NSEG zero-padded) ----
    for (int idx = tid; idx < D10 * SD; idx += BLOCK) {
        int c = idx / SD, t = idx - c * SD;
        float d = 0.f, r = 0.f;
        if (t < NSEG) {
            float p1 = pb[c * LPATH + t + 1];
            d = p1 - pb[c * LPATH + t];
            r = pb[c * LPATH + NSEG] - p1;
        }
        dTT[idx] = d;
        RT [idx] = r;
    }
    // zero pad A rows 250..255 and B cols 110..111 in BOTH buffers (once)
    for (int idx = tid; idx < 2 * 4 * (NROW - NROWA) * 8; idx += BLOCK) {
        int bufi = idx / (4 * 6 * 8);
        int rem  = idx - bufi * (4 * 6 * 8);
        int kg   = rem / (6 * 8);
        int rr   = rem - kg * (6 * 8);
        int o = (kg * NROW + NROWA) * 8 + rr;
        AhiS[bufi][o] = 0; AloS[bufi][o] = 0;
    }
    if (tid < 2 * 4 * 2 * 8) {
        int bufi = tid >> 6;
        int rem  = tid & 63;
        int kg   = rem >> 4;
        int rr   = rem & 15;
        int o = (kg * NCOL + NCOLA) * 8 + rr;
        BhiS[bufi][o] = 0; BloS[bufi][o] = 0;
    }

    // ---- scan identity (threads < 250): row = q*250 + tid ----
    const int grow = q * NROWA + tid;
    const int g   = grow / 100;
    const int m3  = grow - g * 100;
    const int c2  = m3 / 10;
    const int c3  = m3 - c2 * 10;
    const int goff = g * SD, c2off = c2 * SD, c3off = c3 * SD;

    const int lane = tid & 63;
    const int wv   = tid >> 6;      // 8 waves x 32 rows each
    const int rl   = lane & 15;
    const int kgl  = lane >> 4;

    float s1 = 0.f, s2 = 0.f, s3 = 0.f;
    f32x4 acc[2][7];
#pragma unroll
    for (int i = 0; i < 2; ++i)
#pragma unroll
        for (int nt = 0; nt < 7; ++nt) acc[i][nt] = f32x4{0.f, 0.f, 0.f, 0.f};

    // produce chunk (kc0) into buffer pp. Scan on waves 0-3; B-build on
    // waves 4-7 (disjoint waves -> co-schedulable with consume MFMAs).
    auto produce = [&](int pp, int kc0) {
        if (tid < NROWA) {
#pragma unroll
            for (int w0 = 0; w0 < KC; w0 += 4) {
                float4 g4 = *(const float4*)&dTT[goff  + kc0 + w0];
                float4 a4 = *(const float4*)&dTT[c2off + kc0 + w0];
                float4 b4 = *(const float4*)&dTT[c3off + kc0 + w0];
                float ga[4] = {g4.x, g4.y, g4.z, g4.w};
                float aa[4] = {a4.x, a4.y, a4.z, a4.w};
                float ba[4] = {b4.x, b4.y, b4.z, b4.w};
                unsigned hw[4], lw[4];
#pragma unroll
                for (int j = 0; j < 4; ++j) {
                    float dg = ga[j], d2 = aa[j], d3 = ba[j];
                    float u24 = s2 + (s1 + dg * 0.25f)     * d2 * (1.f / 3.f);
                    float u25 = s2 + (s1 + dg * 0.2f)      * d2 * 0.25f;
                    float u23 = s2 + (s1 + dg * (1.f/3.f)) * d2 * 0.5f;
                    float w1v = s3 + u24 * d3 * 0.5f;
                    float w0h = 0.5f * (s3 + u25 * d3 * (1.f / 3.f));
                    s3 += u23 * d3;
                    s2 += (s1 + dg * 0.5f) * d2;
                    s1 += dg;                     // d=0 pads leave state fixed
                    hw[j] = pack_split(w1v, w0h, lw[j]);  // k=2u: W1, 2u+1: W0h
                }
                const int ai = ((w0 >> 2) * NROW + tid) * 8;
                *(uint4*)&AhiS[pp][ai] = make_uint4(hw[0], hw[1], hw[2], hw[3]);
                *(uint4*)&AloS[pp][ai] = make_uint4(lw[0], lw[1], lw[2], lw[3]);
            }
        } else if (tid >= 256) {
            for (int s = tid - 256; s < 4 * NCOLA; s += 256) {
                const int cb  = s >> 2;
                const int kgB = s & 3;
                int c4o, ebo = 0;
                if (cb < 100) { int c4 = cb / 10; ebo = (cb - c4 * 10) * SD; c4o = c4 * SD; }
                else          { c4o = (cb - 100) * SD; }
                const int u0 = kc0 + kgB * 4;
                float4 d4 = *(const float4*)&dTT[c4o + u0];
                float da[4] = {d4.x, d4.y, d4.z, d4.w};
                unsigned hw[4], lw[4];
                if (cb < 100) {
                    float4 e4 = *(const float4*)&dTT[ebo + u0];
                    float4 r4 = *(const float4*)&RT [ebo + u0];
                    float ea[4] = {e4.x, e4.y, e4.z, e4.w};
                    float ra[4] = {r4.x, r4.y, r4.z, r4.w};
#pragma unroll
                    for (int j = 0; j < 4; ++j)
                        hw[j] = pack_split(da[j] * ra[j], da[j] * ea[j], lw[j]);
                } else {        // level-4 aug cols: B1 = d, B0 = 0
#pragma unroll
                    for (int j = 0; j < 4; ++j)
                        hw[j] = pack_split(da[j], 0.f, lw[j]);
                }
                const int bi = (kgB * NCOL + cb) * 8;
                *(uint4*)&BhiS[pp][bi] = make_uint4(hw[0], hw[1], hw[2], hw[3]);
                *(uint4*)&BloS[pp][bi] = make_uint4(lw[0], lw[1], lw[2], lw[3]);
            }
        }
    };

    __syncthreads();                 // tables + pads ready
    produce(0, 0);
    __syncthreads();                 // buf0 ready

    for (int ch = 0; ch < NCH; ++ch) {
        const int p = ch & 1;
        // ---- fragment loads for chunk ch (issue early, in-order LDS) ----
        bf16x8 bh[7], bl[7];
#pragma unroll
        for (int nt = 0; nt < 7; ++nt) {
            const int bi = (kgl * NCOL + nt * 16 + rl) * 8;
            bh[nt] = *(const bf16x8*)&BhiS[p][bi];
            bl[nt] = *(const bf16x8*)&BloS[p][bi];
        }
        bf16x8 ah[2], al[2];
#pragma unroll
        for (int i = 0; i < 2; ++i) {
            const int ai = (kgl * NROW + wv * 32 + i * 16 + rl) * 8;
            ah[i] = *(const bf16x8*)&AhiS[p][ai];
            al[i] = *(const bf16x8*)&AloS[p][ai];
        }
        // ---- produce chunk ch+1 into the other buffer (overlaps MFMA) ----
        if (ch + 1 < NCH) produce(p ^ 1, (ch + 1) * KC);
        // ---- 2 M-tiles x 7 N-tiles x 4 split-term MFMAs ----
#pragma unroll
        for (int i = 0; i < 2; ++i)
#pragma unroll
            for (int nt = 0; nt < 7; ++nt) {
                acc[i][nt] = __builtin_amdgcn_mfma_f32_16x16x32_bf16(ah[i], bh[nt], acc[i][nt], 0, 0, 0);
                acc[i][nt] = __builtin_amdgcn_mfma_f32_16x16x32_bf16(ah[i], bl[nt], acc[i][nt], 0, 0, 0);
                acc[i][nt] = __builtin_amdgcn_mfma_f32_16x16x32_bf16(al[i], bh[nt], acc[i][nt], 0, 0, 0);
                acc[i][nt] = __builtin_amdgcn_mfma_f32_16x16x32_bf16(al[i], bl[nt], acc[i][nt], 0, 0, 0);
            }
        __syncthreads();             // buf[p^1] written; buf[p] reads done
    }

    // ---- epilogue (registers only; no barrier) ----
    float* ob = out + (size_t)b * OUT_PER_B;
    if (tid < NROWA) {
        ob[110 + grow] = s3;                       // level 3
        if (c3 == 0) ob[10 + g * 10 + c2] = s2;    // level 2
        if (m3 == 0) ob[g] = s1;                   // level 1
    }
    // D layout (m89-verified): col = lane&15, row = (lane>>4)*4 + reg
#pragma unroll
    for (int i = 0; i < 2; ++i) {
#pragma unroll
        for (int r = 0; r < 4; ++r) {
            const int prow = wv * 32 + i * 16 + kgl * 4 + r;
            if (prow < NROWA) {
                const int gr = q * NROWA + prow;
#pragma unroll
                for (int nt = 0; nt < 7; ++nt) {
                    const int col = nt * 16 + rl;
                    const float v = acc[i][nt][r];
                    if (col < 100)
                        ob[11110 + (size_t)gr * 100 + col] = v;   // level 5
                    else if (col < NCOLA)
                        ob[1110 + gr * 10 + (col - 100)] = v;     // level 4
                }
            }
        }
    }
}

extern "C" void kernel_launch(void* const* d_in, const int* in_sizes, int n_in,
                              void* d_out, int out_size, void* d_ws, size_t ws_size,
                              hipStream_t stream) {
    const float* path = (const float*)d_in[0];
    float* out = (float*)d_out;
    int B = in_sizes[0] / (D10 * LPATH);   // 256
    sig_kernel<<<B * 4, BLOCK, 0, stream>>>(path, out);
}